// Round 8
// baseline (442.190 us; speedup 1.0000x reference)
//
#include <hip/hip_runtime.h>
#include <cstdint>

#define K_DIM 4096
#define ROWB 13              // log2(K_DIM*2) byte row stride
#define NU   (K_DIM / 32)    // 128 K-units of 32 cols

typedef __bf16 bf16x8 __attribute__((ext_vector_type(8)));
typedef float f32x4 __attribute__((ext_vector_type(4)));

// round-to-nearest-even float -> bf16 bits
__device__ inline unsigned short f2bf(float f) {
    union { float f; unsigned int u; } v; v.f = f;
    unsigned int u = v.u;
    return (unsigned short)((u + 0x7FFFu + ((u >> 16) & 1u)) >> 16);
}

__device__ __forceinline__ void gload16(const void* g, void* l) {
    __builtin_amdgcn_global_load_lds(
        (const __attribute__((address_space(1))) unsigned int*)g,
        (__attribute__((address_space(3))) unsigned int*)l,
        16, 0, 0);
}

// fused dequant of both operands: out[e] = bf16(q[e] * s[e/16])
__global__ __launch_bounds__(256) void dequant2_kernel(
        const float* __restrict__ qx, const float* __restrict__ sx,
        unsigned short* __restrict__ xd, long t8x,
        const float* __restrict__ qw, const float* __restrict__ sw,
        unsigned short* __restrict__ wd, long t8w) {
    long i = (long)blockIdx.x * blockDim.x + threadIdx.x;
    if (i >= t8x + t8w) return;
    const float* q; const float* s; unsigned short* o;
    if (i < t8x) { q = qx; s = sx; o = xd; }
    else         { q = qw; s = sw; o = wd; i -= t8x; }
    long e = i * 8;
    float sc = s[e >> 4];
    float4 v0 = *(const float4*)(q + e);
    float4 v1 = *(const float4*)(q + e + 4);
    union { unsigned short h[8]; uint4 u; } ov;
    ov.h[0] = f2bf(v0.x * sc); ov.h[1] = f2bf(v0.y * sc);
    ov.h[2] = f2bf(v0.z * sc); ov.h[3] = f2bf(v0.w * sc);
    ov.h[4] = f2bf(v1.x * sc); ov.h[5] = f2bf(v1.y * sc);
    ov.h[6] = f2bf(v1.z * sc); ov.h[7] = f2bf(v1.w * sc);
    *(uint4*)(o + e) = ov.u;
}

// ---------------- 256x256 bf16 GEMM, A-in-LDS / B-from-L2 ----------------
// 8 waves (2M x 4N), per-wave 128x64 out, 16x16x32 MFMA (r3-proven frag
// pattern, 0 bank conflicts). LDS holds ONLY A: 4 slots x 16 KB = 64 KB,
// staged via global_load_lds with the chunk-XOR swizzle pre-applied to the
// per-lane GLOBAL address. B-fragments are loaded per-wave from GLOBAL
// (L2-resident: n-major XCD swizzle keeps each XCD on 2 B-panels = 4 MB)
// into registers, double-buffered one unit ahead.
// Per-unit LDS traffic drops 128KB -> 80KB (below the MFMA-pipe time).
// One barrier/unit; boundary vmcnt(2) leaves only Ast(u+2) outstanding.

__global__ __launch_bounds__(512, 2) void gemm256_kernel(
        const unsigned short* __restrict__ A,   // [M][K] bf16
        const unsigned short* __restrict__ B,   // [N][K] bf16
        const float* __restrict__ sg1, const float* __restrict__ sg2,
        const float* __restrict__ bias,
        float* __restrict__ out, int M, int N) {
    __shared__ __align__(16) char lds[65536];   // 4 slots x 16 KB (A only)

    const int tid  = threadIdx.x;
    const int lane = tid & 63;
    const int wid  = tid >> 6;       // 0..7
    const int wm   = wid >> 2;       // 0..1
    const int wn   = wid & 3;        // 0..3
    const int l15  = lane & 15;
    const int cb   = (lane >> 4) << 4;                        // frag chunk byte
    const int scb  = ((lane & 3) ^ ((lane >> 3) & 3)) << 4;   // staging src chunk

    // XCD-aware bijective swizzle, n-major: each XCD owns 2 B-panels (4 MB)
    const int nbm = M >> 8;                  // 32 m-tiles
    const int nwg = nbm * (N >> 8);
    const int cpx = nwg >> 3;
    const int bid = blockIdx.x;
    const int swz = (bid & 7) * cpx + (bid >> 3);
    const int tile_n = (swz / nbm) << 8;
    const int tile_m = (swz % nbm) << 8;

    // A: per-thread global staging cursors (unit-0 addresses); +u*64 per unit
    const int grow = lane >> 2;      // row within 16-row group
    const char* gA0 = (const char*)A +
        ((size_t)(tile_m + 32 * wid + grow) << ROWB) + scb;
    const char* gA1 = gA0 + ((size_t)16 << ROWB);
    const int dA0 = wid * 2048;      // LDS staging dest (wave-uniform) in 16KB slot

    // A fragment read offsets (swizzle XOR invariant across +16-row steps)
    const int arow = wm * 128 + l15;
    const int aoff = arow * 64 + (cb ^ (((arow >> 1) & 3) << 4));  // +mb*1024

    // B: per-thread global frag cursors; frag nb at +nb*16 rows; +u*64 per unit
    const char* gBf = (const char*)B +
        ((size_t)(tile_n + wn * 64 + l15) << ROWB) + cb;

    f32x4 acc[8][4];
#pragma unroll
    for (int mb = 0; mb < 8; ++mb)
#pragma unroll
        for (int nb = 0; nb < 4; ++nb) acc[mb][nb] = (f32x4){0.f, 0.f, 0.f, 0.f};

    bf16x8 bAr[4], bBr[4];

    // prologue: B(0) -> bAr, then A-stage units 0,1 into slots 0,1
#pragma unroll
    for (int nb = 0; nb < 4; ++nb)
        bAr[nb] = *(const bf16x8*)(gBf + ((size_t)nb << 17));
#pragma unroll
    for (int pu = 0; pu < 2; ++pu) {
        char* Sb = lds + pu * 16384;
        const int kb = pu << 6;
        gload16(gA0 + kb, Sb + dA0);
        gload16(gA1 + kb, Sb + dA0 + 1024);
    }
    // drains B(0) + Ast(0); leaves Ast(1) (2 loads) outstanding
    asm volatile("s_waitcnt vmcnt(2)" ::: "memory");
    __builtin_amdgcn_s_barrier();

    // unit body: compute unit U from slot CUR using BCUR; load B(U+1)->BNXT;
    // stage A(U+2) into slot STG; boundary vmcnt(2) leaves only Ast(U+2).
#define UNIT_BODY(U, CUR, STG, BCUR, BNXT) do {                              \
    const int un = ((U) + 1 < NU) ? (U) + 1 : (NU - 1);                      \
    const int us = ((U) + 2 < NU) ? (U) + 2 : (NU - 1);                      \
    _Pragma("unroll")                                                        \
    for (int nb = 0; nb < 4; ++nb)                                           \
        BNXT[nb] = *(const bf16x8*)(gBf + ((size_t)nb << 17) + un * 64);     \
    gload16(gA0 + (us << 6), lds + (STG) + dA0);                             \
    gload16(gA1 + (us << 6), lds + (STG) + dA0 + 1024);                      \
    bf16x8 afr[8];                                                           \
    _Pragma("unroll")                                                        \
    for (int mb = 0; mb < 8; ++mb)                                           \
        afr[mb] = *(const bf16x8*)(lds + (CUR) + aoff + mb * 1024);          \
    __builtin_amdgcn_s_setprio(1);                                           \
    _Pragma("unroll")                                                        \
    for (int mb = 0; mb < 8; ++mb)                                           \
        _Pragma("unroll")                                                    \
        for (int nb = 0; nb < 4; ++nb)                                       \
            acc[mb][nb] = __builtin_amdgcn_mfma_f32_16x16x32_bf16(           \
                afr[mb], BCUR[nb], acc[mb][nb], 0, 0, 0);                    \
    __builtin_amdgcn_s_setprio(0);                                           \
    asm volatile("s_waitcnt vmcnt(2)" ::: "memory");                         \
    __builtin_amdgcn_s_barrier();                                            \
} while (0)

    for (int ub = 0; ub < NU; ub += 4) {
        UNIT_BODY(ub + 0, 0,     32768, bAr, bBr);
        UNIT_BODY(ub + 1, 16384, 49152, bBr, bAr);
        UNIT_BODY(ub + 2, 32768, 0,     bAr, bBr);
        UNIT_BODY(ub + 3, 49152, 16384, bBr, bAr);
    }
#undef UNIT_BODY

    // epilogue: C/D layout col=lane&15, row=(lane>>4)*4+j
    const float gs = sg1[0] * sg2[0];
    const int row0 = tile_m + wm * 128 + ((lane >> 4) << 2);
    const int col0 = tile_n + wn * 64 + l15;
    float bv[4];
#pragma unroll
    for (int nb = 0; nb < 4; ++nb) bv[nb] = bias[col0 + nb * 16];
#pragma unroll
    for (int mb = 0; mb < 8; ++mb)
#pragma unroll
        for (int nb = 0; nb < 4; ++nb) {
            const int col = col0 + nb * 16;
#pragma unroll
            for (int j = 0; j < 4; ++j)
                out[(size_t)(row0 + mb * 16 + j) * N + col] =
                    acc[mb][nb][j] * gs + bv[nb];
        }
}

// ---------------- fallback: fused-dequant 128^2 GEMM (ws too small) ----------------
__global__ __launch_bounds__(256) void gemm_fused_kernel(
        const float* __restrict__ qx, const float* __restrict__ sx,
        const float* __restrict__ qw, const float* __restrict__ sw,
        const float* __restrict__ sg1, const float* __restrict__ sg2,
        const float* __restrict__ bias,
        float* __restrict__ out, int M, int N) {
    __shared__ __align__(16) unsigned short As[128 * 32];
    __shared__ __align__(16) unsigned short Bs[128 * 32];
    const int tid  = threadIdx.x;
    const int lane = tid & 63;
    const int wid  = tid >> 6;
    const int tile_n = blockIdx.x * 128;
    const int tile_m = blockIdx.y * 128;
    const int wm = wid >> 1, wn = wid & 1;
    f32x4 acc[16];
#pragma unroll
    for (int i = 0; i < 16; ++i) acc[i] = (f32x4){0.f, 0.f, 0.f, 0.f};
    const int l15 = lane & 15;
    const int lk  = (lane >> 4) * 8;
    for (int kt = 0; kt < K_DIM / 32; ++kt) {
#pragma unroll
        for (int cc = 0; cc < 2; ++cc) {
            const int c   = tid + cc * 256;
            const int row = c >> 2;
            const int col = (c & 3) * 8;
            const int gk  = kt * 32 + col;
            {
                const float* qp = qx + (long)(tile_m + row) * K_DIM + gk;
                float s = sx[(long)(tile_m + row) * (K_DIM / 16) + (gk >> 4)];
                float4 a0 = *(const float4*)qp;
                float4 a1 = *(const float4*)(qp + 4);
                union { unsigned short h[8]; uint4 u; } o;
                o.h[0] = f2bf(a0.x * s); o.h[1] = f2bf(a0.y * s);
                o.h[2] = f2bf(a0.z * s); o.h[3] = f2bf(a0.w * s);
                o.h[4] = f2bf(a1.x * s); o.h[5] = f2bf(a1.y * s);
                o.h[6] = f2bf(a1.z * s); o.h[7] = f2bf(a1.w * s);
                *(uint4*)&As[row * 32 + col] = o.u;
            }
            {
                const float* qp = qw + (long)(tile_n + row) * K_DIM + gk;
                float s = sw[(long)(tile_n + row) * (K_DIM / 16) + (gk >> 4)];
                float4 a0 = *(const float4*)qp;
                float4 a1 = *(const float4*)(qp + 4);
                union { unsigned short h[8]; uint4 u; } o;
                o.h[0] = f2bf(a0.x * s); o.h[1] = f2bf(a0.y * s);
                o.h[2] = f2bf(a0.z * s); o.h[3] = f2bf(a0.w * s);
                o.h[4] = f2bf(a1.x * s); o.h[5] = f2bf(a1.y * s);
                o.h[6] = f2bf(a1.z * s); o.h[7] = f2bf(a1.w * s);
                *(uint4*)&Bs[row * 32 + col] = o.u;
            }
        }
        __syncthreads();
        const unsigned short* pa = As + (wm * 64 + l15) * 32 + lk;
        const unsigned short* pb = Bs + (wn * 64 + l15) * 32 + lk;
        bf16x8 a[4], b[4];
#pragma unroll
        for (int i = 0; i < 4; ++i) {
            a[i] = *(const bf16x8*)(pa + i * 16 * 32);
            b[i] = *(const bf16x8*)(pb + i * 16 * 32);
        }
#pragma unroll
        for (int mi = 0; mi < 4; ++mi)
#pragma unroll
            for (int ni = 0; ni < 4; ++ni)
                acc[mi * 4 + ni] = __builtin_amdgcn_mfma_f32_16x16x32_bf16(
                    a[mi], b[ni], acc[mi * 4 + ni], 0, 0, 0);
        __syncthreads();
    }
    const float gs = sg1[0] * sg2[0];
    const int row0 = tile_m + wm * 64 + (lane >> 4) * 4;
    const int col0 = tile_n + wn * 64 + l15;
#pragma unroll
    for (int mi = 0; mi < 4; ++mi)
#pragma unroll
        for (int ni = 0; ni < 4; ++ni) {
            const int col = col0 + ni * 16;
            const float bv = bias[col];
#pragma unroll
            for (int j = 0; j < 4; ++j)
                out[(long)(row0 + mi * 16 + j) * N + col] =
                    acc[mi * 4 + ni][j] * gs + bv;
        }
}

extern "C" void kernel_launch(void* const* d_in, const int* in_sizes, int n_in,
                              void* d_out, int out_size, void* d_ws, size_t ws_size,
                              hipStream_t stream) {
    const float* qx   = (const float*)d_in[0];
    const float* sx   = (const float*)d_in[1];
    const float* sc   = (const float*)d_in[2];
    const float* qw   = (const float*)d_in[3];
    const float* sw   = (const float*)d_in[4];
    const float* swg  = (const float*)d_in[5];
    const float* bias = (const float*)d_in[6];
    float* out = (float*)d_out;

    const int M = in_sizes[0] / K_DIM;   // 8192
    const int N = in_sizes[3] / K_DIM;   // 4096

    const size_t needA = (size_t)M * K_DIM * sizeof(unsigned short);
    const size_t needB = (size_t)N * K_DIM * sizeof(unsigned short);

    if (ws_size >= needA + needB) {
        unsigned short* xd = (unsigned short*)d_ws;
        unsigned short* wd = (unsigned short*)((char*)d_ws + needA);
        long t8x = (long)M * K_DIM / 8;
        long t8w = (long)N * K_DIM / 8;
        long tot = t8x + t8w;
        dequant2_kernel<<<(int)((tot + 255) / 256), 256, 0, stream>>>(
            qx, sx, xd, t8x, qw, sw, wd, t8w);
        const int nwg = (M / 256) * (N / 256);
        gemm256_kernel<<<nwg, 512, 0, stream>>>(xd, wd, sc, swg, bias, out, M, N);
    } else {
        dim3 grid(N / 128, M / 128);
        gemm_fused_kernel<<<grid, 256, 0, stream>>>(
            qx, sx, qw, sw, sc, swg, bias, out, M, N);
    }
}

// Round 9
// 302.748 us; speedup vs baseline: 1.4606x; 1.4606x over previous
//
#include <hip/hip_runtime.h>
#include <cstdint>

#define K_DIM 4096
#define ROWB 13              // log2(K_DIM*2) byte row stride
#define NU64 (K_DIM / 64)    // 64 K-units of 64 cols

typedef __bf16 bf16x8 __attribute__((ext_vector_type(8)));
typedef float f32x4 __attribute__((ext_vector_type(4)));

// round-to-nearest-even float -> bf16 bits
__device__ inline unsigned short f2bf(float f) {
    union { float f; unsigned int u; } v; v.f = f;
    unsigned int u = v.u;
    return (unsigned short)((u + 0x7FFFu + ((u >> 16) & 1u)) >> 16);
}

__device__ __forceinline__ void gload16(const void* g, void* l) {
    __builtin_amdgcn_global_load_lds(
        (const __attribute__((address_space(1))) unsigned int*)g,
        (__attribute__((address_space(3))) unsigned int*)l,
        16, 0, 0);
}

// fused dequant of both operands: out[e] = bf16(q[e] * s[e/16])
__global__ __launch_bounds__(256) void dequant2_kernel(
        const float* __restrict__ qx, const float* __restrict__ sx,
        unsigned short* __restrict__ xd, long t8x,
        const float* __restrict__ qw, const float* __restrict__ sw,
        unsigned short* __restrict__ wd, long t8w) {
    long i = (long)blockIdx.x * blockDim.x + threadIdx.x;
    if (i >= t8x + t8w) return;
    const float* q; const float* s; unsigned short* o;
    if (i < t8x) { q = qx; s = sx; o = xd; }
    else         { q = qw; s = sw; o = wd; i -= t8x; }
    long e = i * 8;
    float sc = s[e >> 4];
    float4 v0 = *(const float4*)(q + e);
    float4 v1 = *(const float4*)(q + e + 4);
    union { unsigned short h[8]; uint4 u; } ov;
    ov.h[0] = f2bf(v0.x * sc); ov.h[1] = f2bf(v0.y * sc);
    ov.h[2] = f2bf(v0.z * sc); ov.h[3] = f2bf(v0.w * sc);
    ov.h[4] = f2bf(v1.x * sc); ov.h[5] = f2bf(v1.y * sc);
    ov.h[6] = f2bf(v1.z * sc); ov.h[7] = f2bf(v1.w * sc);
    *(uint4*)(o + e) = ov.u;
}

// ---------------- 256x256 bf16 GEMM, BK=64 (overhead amortization) ----------------
// 8 waves (2M x 4N), per-wave 128x64 out, 16x16x32 MFMA (r3-proven frag
// pattern). K in 64-wide units; 2 LDS slots x 64KB (A 32KB + B 32KB) =
// 128 KiB. Stage for unit u+1 issued at TOP of unit u (~3000 cyc in
// flight >> HBM latency), so the boundary vmcnt(0) is a cheap drain.
// Per unit: 2 phases x {12 ds_read_b128 -> bar -> setprio + 32 MFMA}.
// LDS swizzle (128B rows): 16B chunk c of row r stored at c ^ (r&7);
// inverse pre-applied to per-lane GLOBAL source (LDS dest stays linear).

__global__ __launch_bounds__(512, 2) void gemm256_kernel(
        const unsigned short* __restrict__ A,   // [M][K] bf16
        const unsigned short* __restrict__ B,   // [N][K] bf16
        const float* __restrict__ sg1, const float* __restrict__ sg2,
        const float* __restrict__ bias,
        float* __restrict__ out, int M, int N) {
    __shared__ __align__(16) char lds[131072];   // 2 slots x 64 KB

    const int tid  = threadIdx.x;
    const int lane = tid & 63;
    const int wid  = tid >> 6;       // 0..7
    const int wm   = wid >> 2;       // 0..1
    const int wn   = wid & 3;        // 0..3
    const int l15  = lane & 15;
    const int cb4  = lane >> 4;      // 0..3: 16B chunk within 32-col ksub
    const int ax   = l15 & 7;        // read-side row XOR

    // XCD-aware bijective block swizzle (nwg % 8 == 0)
    const int nbn = N >> 8;
    const int nwg = (M >> 8) * nbn;
    const int cpx = nwg >> 3;
    const int bid = blockIdx.x;
    const int swz = (bid & 7) * cpx + (bid >> 3);
    const int tile_m = (swz / nbn) << 8;
    const int tile_n = (swz % nbn) << 8;

    // staging: per pass, 512 threads cover 64 rows x 8 chunks (16B) of a
    // 128B-wide row; 4 passes cover 256 rows. wave w -> rows 8w..8w+7.
    const int scb = ((lane & 7) ^ (lane >> 3)) << 4;   // pre-swizzled src chunk
    const char* gA0 = (const char*)A +
        ((size_t)(tile_m + 8 * wid + (lane >> 3)) << ROWB) + scb;
    const char* gB0 = (const char*)B +
        ((size_t)(tile_n + 8 * wid + (lane >> 3)) << ROWB) + scb;
    const int dA = wid * 1024;       // wave-uniform LDS dest within a pass

    // fragment read offsets: row r=(..)+l15 -> r&7 = l15&7 invariant
    const int arow = wm * 128 + l15;
    const int aK0 = arow * 128 + ((cb4 ^ ax) << 4);            // +mb*2048
    const int aK1 = arow * 128 + (((4 + cb4) ^ ax) << 4);
    const int brow = wn * 64 + l15;
    const int bK0 = 32768 + brow * 128 + ((cb4 ^ ax) << 4);    // +nb*2048
    const int bK1 = 32768 + brow * 128 + (((4 + cb4) ^ ax) << 4);

    f32x4 acc[8][4];
#pragma unroll
    for (int mb = 0; mb < 8; ++mb)
#pragma unroll
        for (int nb = 0; nb < 4; ++nb) acc[mb][nb] = (f32x4){0.f, 0.f, 0.f, 0.f};

    // prologue: stage unit 0 into slot 0
#pragma unroll
    for (int p = 0; p < 4; ++p) {
        gload16(gA0 + ((size_t)(p * 64) << ROWB), lds + p * 8192 + dA);
        gload16(gB0 + ((size_t)(p * 64) << ROWB), lds + 32768 + p * 8192 + dA);
    }
    asm volatile("s_waitcnt vmcnt(0)" ::: "memory");
    __builtin_amdgcn_s_barrier();

    // unit body: stage u+1 (issued first, waited at boundary), 2 phases.
#define UNIT_BODY(U, CUR, STG) do {                                          \
    const int su  = ((U) + 1 < NU64) ? (U) + 1 : (NU64 - 1);                 \
    const size_t sub = (size_t)su << 7;                                      \
    _Pragma("unroll")                                                        \
    for (int p = 0; p < 4; ++p) {                                            \
        gload16(gA0 + ((size_t)(p * 64) << ROWB) + sub,                      \
                lds + (STG) + p * 8192 + dA);                                \
        gload16(gB0 + ((size_t)(p * 64) << ROWB) + sub,                      \
                lds + (STG) + 32768 + p * 8192 + dA);                        \
    }                                                                        \
    {                                                                        \
        bf16x8 afr[8], bfr[4];                                               \
        _Pragma("unroll")                                                    \
        for (int nb = 0; nb < 4; ++nb)                                       \
            bfr[nb] = *(const bf16x8*)(lds + (CUR) + bK0 + nb * 2048);       \
        _Pragma("unroll")                                                    \
        for (int mb = 0; mb < 8; ++mb)                                       \
            afr[mb] = *(const bf16x8*)(lds + (CUR) + aK0 + mb * 2048);       \
        __builtin_amdgcn_s_barrier();                                        \
        __builtin_amdgcn_s_setprio(1);                                       \
        _Pragma("unroll")                                                    \
        for (int mb = 0; mb < 8; ++mb)                                       \
            _Pragma("unroll")                                                \
            for (int nb = 0; nb < 4; ++nb)                                   \
                acc[mb][nb] = __builtin_amdgcn_mfma_f32_16x16x32_bf16(       \
                    afr[mb], bfr[nb], acc[mb][nb], 0, 0, 0);                 \
        __builtin_amdgcn_s_setprio(0);                                       \
    }                                                                        \
    {                                                                        \
        bf16x8 afr[8], bfr[4];                                               \
        _Pragma("unroll")                                                    \
        for (int nb = 0; nb < 4; ++nb)                                       \
            bfr[nb] = *(const bf16x8*)(lds + (CUR) + bK1 + nb * 2048);       \
        _Pragma("unroll")                                                    \
        for (int mb = 0; mb < 8; ++mb)                                       \
            afr[mb] = *(const bf16x8*)(lds + (CUR) + aK1 + mb * 2048);       \
        __builtin_amdgcn_s_barrier();                                        \
        __builtin_amdgcn_s_setprio(1);                                       \
        _Pragma("unroll")                                                    \
        for (int mb = 0; mb < 8; ++mb)                                       \
            _Pragma("unroll")                                                \
            for (int nb = 0; nb < 4; ++nb)                                   \
                acc[mb][nb] = __builtin_amdgcn_mfma_f32_16x16x32_bf16(       \
                    afr[mb], bfr[nb], acc[mb][nb], 0, 0, 0);                 \
        __builtin_amdgcn_s_setprio(0);                                       \
    }                                                                        \
    asm volatile("s_waitcnt vmcnt(0)" ::: "memory");                         \
    __builtin_amdgcn_s_barrier();                                            \
} while (0)

    for (int up = 0; up < NU64; up += 2) {
        UNIT_BODY(up,     0,     65536);
        UNIT_BODY(up + 1, 65536, 0);
    }
#undef UNIT_BODY

    // epilogue: C/D layout col=lane&15, row=(lane>>4)*4+j
    const float gs = sg1[0] * sg2[0];
    const int row0 = tile_m + wm * 128 + (cb4 << 2);
    const int col0 = tile_n + wn * 64 + l15;
    float bv[4];
#pragma unroll
    for (int nb = 0; nb < 4; ++nb) bv[nb] = bias[col0 + nb * 16];
#pragma unroll
    for (int mb = 0; mb < 8; ++mb)
#pragma unroll
        for (int nb = 0; nb < 4; ++nb) {
            const int col = col0 + nb * 16;
#pragma unroll
            for (int j = 0; j < 4; ++j)
                out[(size_t)(row0 + mb * 16 + j) * N + col] =
                    acc[mb][nb][j] * gs + bv[nb];
        }
}

// ---------------- fallback: fused-dequant 128^2 GEMM (ws too small) ----------------
__global__ __launch_bounds__(256) void gemm_fused_kernel(
        const float* __restrict__ qx, const float* __restrict__ sx,
        const float* __restrict__ qw, const float* __restrict__ sw,
        const float* __restrict__ sg1, const float* __restrict__ sg2,
        const float* __restrict__ bias,
        float* __restrict__ out, int M, int N) {
    __shared__ __align__(16) unsigned short As[128 * 32];
    __shared__ __align__(16) unsigned short Bs[128 * 32];
    const int tid  = threadIdx.x;
    const int lane = tid & 63;
    const int wid  = tid >> 6;
    const int tile_n = blockIdx.x * 128;
    const int tile_m = blockIdx.y * 128;
    const int wm = wid >> 1, wn = wid & 1;
    f32x4 acc[16];
#pragma unroll
    for (int i = 0; i < 16; ++i) acc[i] = (f32x4){0.f, 0.f, 0.f, 0.f};
    const int l15 = lane & 15;
    const int lk  = (lane >> 4) * 8;
    for (int kt = 0; kt < K_DIM / 32; ++kt) {
#pragma unroll
        for (int cc = 0; cc < 2; ++cc) {
            const int c   = tid + cc * 256;
            const int row = c >> 2;
            const int col = (c & 3) * 8;
            const int gk  = kt * 32 + col;
            {
                const float* qp = qx + (long)(tile_m + row) * K_DIM + gk;
                float s = sx[(long)(tile_m + row) * (K_DIM / 16) + (gk >> 4)];
                float4 a0 = *(const float4*)qp;
                float4 a1 = *(const float4*)(qp + 4);
                union { unsigned short h[8]; uint4 u; } o;
                o.h[0] = f2bf(a0.x * s); o.h[1] = f2bf(a0.y * s);
                o.h[2] = f2bf(a0.z * s); o.h[3] = f2bf(a0.w * s);
                o.h[4] = f2bf(a1.x * s); o.h[5] = f2bf(a1.y * s);
                o.h[6] = f2bf(a1.z * s); o.h[7] = f2bf(a1.w * s);
                *(uint4*)&As[row * 32 + col] = o.u;
            }
            {
                const float* qp = qw + (long)(tile_n + row) * K_DIM + gk;
                float s = sw[(long)(tile_n + row) * (K_DIM / 16) + (gk >> 4)];
                float4 a0 = *(const float4*)qp;
                float4 a1 = *(const float4*)(qp + 4);
                union { unsigned short h[8]; uint4 u; } o;
                o.h[0] = f2bf(a0.x * s); o.h[1] = f2bf(a0.y * s);
                o.h[2] = f2bf(a0.z * s); o.h[3] = f2bf(a0.w * s);
                o.h[4] = f2bf(a1.x * s); o.h[5] = f2bf(a1.y * s);
                o.h[6] = f2bf(a1.z * s); o.h[7] = f2bf(a1.w * s);
                *(uint4*)&Bs[row * 32 + col] = o.u;
            }
        }
        __syncthreads();
        const unsigned short* pa = As + (wm * 64 + l15) * 32 + lk;
        const unsigned short* pb = Bs + (wn * 64 + l15) * 32 + lk;
        bf16x8 a[4], b[4];
#pragma unroll
        for (int i = 0; i < 4; ++i) {
            a[i] = *(const bf16x8*)(pa + i * 16 * 32);
            b[i] = *(const bf16x8*)(pb + i * 16 * 32);
        }
#pragma unroll
        for (int mi = 0; mi < 4; ++mi)
#pragma unroll
            for (int ni = 0; ni < 4; ++ni)
                acc[mi * 4 + ni] = __builtin_amdgcn_mfma_f32_16x16x32_bf16(
                    a[mi], b[ni], acc[mi * 4 + ni], 0, 0, 0);
        __syncthreads();
    }
    const float gs = sg1[0] * sg2[0];
    const int row0 = tile_m + wm * 64 + (lane >> 4) * 4;
    const int col0 = tile_n + wn * 64 + l15;
#pragma unroll
    for (int mi = 0; mi < 4; ++mi)
#pragma unroll
        for (int ni = 0; ni < 4; ++ni) {
            const int col = col0 + ni * 16;
            const float bv = bias[col];
#pragma unroll
            for (int j = 0; j < 4; ++j)
                out[(long)(row0 + mi * 16 + j) * N + col] =
                    acc[mi * 4 + ni][j] * gs + bv;
        }
}

extern "C" void kernel_launch(void* const* d_in, const int* in_sizes, int n_in,
                              void* d_out, int out_size, void* d_ws, size_t ws_size,
                              hipStream_t stream) {
    const float* qx   = (const float*)d_in[0];
    const float* sx   = (const float*)d_in[1];
    const float* sc   = (const float*)d_in[2];
    const float* qw   = (const float*)d_in[3];
    const float* sw   = (const float*)d_in[4];
    const float* swg  = (const float*)d_in[5];
    const float* bias = (const float*)d_in[6];
    float* out = (float*)d_out;

    const int M = in_sizes[0] / K_DIM;   // 8192
    const int N = in_sizes[3] / K_DIM;   // 4096

    const size_t needA = (size_t)M * K_DIM * sizeof(unsigned short);
    const size_t needB = (size_t)N * K_DIM * sizeof(unsigned short);

    if (ws_size >= needA + needB) {
        unsigned short* xd = (unsigned short*)d_ws;
        unsigned short* wd = (unsigned short*)((char*)d_ws + needA);
        long t8x = (long)M * K_DIM / 8;
        long t8w = (long)N * K_DIM / 8;
        long tot = t8x + t8w;
        dequant2_kernel<<<(int)((tot + 255) / 256), 256, 0, stream>>>(
            qx, sx, xd, t8x, qw, sw, wd, t8w);
        const int nwg = (M / 256) * (N / 256);
        gemm256_kernel<<<nwg, 512, 0, stream>>>(xd, wd, sc, swg, bias, out, M, N);
    } else {
        dim3 grid(N / 128, M / 128);
        gemm_fused_kernel<<<grid, 256, 0, stream>>>(
            qx, sx, qw, sw, sc, swg, bias, out, M, N);
    }
}

// Round 10
// 279.315 us; speedup vs baseline: 1.5831x; 1.0839x over previous
//
#include <hip/hip_runtime.h>
#include <cstdint>

#define K_DIM 4096
#define ROWB 13              // log2(K_DIM*2) byte row stride
#define NT   (K_DIM / 64)   // 64 K-tiles of 64 cols

typedef __bf16 bf16x8 __attribute__((ext_vector_type(8)));
typedef float f32x4 __attribute__((ext_vector_type(4)));

// round-to-nearest-even float -> bf16 bits
__device__ inline unsigned short f2bf(float f) {
    union { float f; unsigned int u; } v; v.f = f;
    unsigned int u = v.u;
    return (unsigned short)((u + 0x7FFFu + ((u >> 16) & 1u)) >> 16);
}

__device__ __forceinline__ void gload16(const void* g, void* l) {
    __builtin_amdgcn_global_load_lds(
        (const __attribute__((address_space(1))) unsigned int*)g,
        (__attribute__((address_space(3))) unsigned int*)l,
        16, 0, 0);
}

// fused dequant of both operands: out[e] = bf16(q[e] * s[e/16])
__global__ __launch_bounds__(256) void dequant2_kernel(
        const float* __restrict__ qx, const float* __restrict__ sx,
        unsigned short* __restrict__ xd, long t8x,
        const float* __restrict__ qw, const float* __restrict__ sw,
        unsigned short* __restrict__ wd, long t8w) {
    long i = (long)blockIdx.x * blockDim.x + threadIdx.x;
    if (i >= t8x + t8w) return;
    const float* q; const float* s; unsigned short* o;
    if (i < t8x) { q = qx; s = sx; o = xd; }
    else         { q = qw; s = sw; o = wd; i -= t8x; }
    long e = i * 8;
    float sc = s[e >> 4];
    float4 v0 = *(const float4*)(q + e);
    float4 v1 = *(const float4*)(q + e + 4);
    union { unsigned short h[8]; uint4 u; } ov;
    ov.h[0] = f2bf(v0.x * sc); ov.h[1] = f2bf(v0.y * sc);
    ov.h[2] = f2bf(v0.z * sc); ov.h[3] = f2bf(v0.w * sc);
    ov.h[4] = f2bf(v1.x * sc); ov.h[5] = f2bf(v1.y * sc);
    ov.h[6] = f2bf(v1.z * sc); ov.h[7] = f2bf(v1.w * sc);
    *(uint4*)(o + e) = ov.u;
}

// ------------- 256x256 bf16 GEMM — m201 8-phase faithful port -------------
// 8 waves (2M x 4N), per-wave 128x64 out. BK=64, 2 LDS buffers x 64KB
// (A[256][64] + B[256][64]). 4 phases per K-tile, each phase:
//   {ds_read subtile || stage 2 gloads} -> bar -> lgkmcnt(0) ->
//   setprio(1) + 16 MFMA (one C-quadrant x K=64) + setprio(0) -> bar
// WAVE-PRIVATE STAGING: each wave stages only LDS rows it reads, in its
// read order -> counted vmcnt legal: vmcnt(4) at ph2 close (drains this
// tile's A-high), vmcnt(2) at tile boundary (leaves next A-high in
// flight). Never drains to 0 in the main loop.
// Swizzle (128B rows): 16B chunk c of row r stored at c ^ (r&7), inverse
// pre-applied to per-lane GLOBAL source (LDS dest linear; r9-verified).

__global__ __launch_bounds__(512, 2) void gemm256_kernel(
        const unsigned short* __restrict__ A,   // [M][K] bf16
        const unsigned short* __restrict__ B,   // [N][K] bf16
        const float* __restrict__ sg1, const float* __restrict__ sg2,
        const float* __restrict__ bias,
        float* __restrict__ out, int M, int N) {
    __shared__ __align__(16) char lds[131072];   // 2 buffers x 64 KB

    const int tid  = threadIdx.x;
    const int lane = tid & 63;
    const int wid  = tid >> 6;       // 0..7
    const int wm   = wid >> 2;       // 0..1
    const int wn   = wid & 3;        // 0..3
    const int l15  = lane & 15;
    const int cb4  = lane >> 4;      // 0..3: 16B chunk within 32-col ksub
    const int rx   = l15 & 7;        // read-side row XOR
    const int xk0  = (cb4 ^ rx) << 4;
    const int xk1  = ((4 + cb4) ^ rx) << 4;

    // XCD-aware bijective block swizzle (nwg % 8 == 0)
    const int nbn = N >> 8;
    const int nwg = (M >> 8) * nbn;
    const int cpx = nwg >> 3;
    const int bid = blockIdx.x;
    const int swz = (bid & 7) * cpx + (bid >> 3);
    const int tile_m = (swz / nbn) << 8;
    const int tile_n = (swz % nbn) << 8;

    // wave-private staging cursors (tile-0 addresses); +t*128 bytes per K-tile
    const int scb = ((lane & 7) ^ ((lane >> 3) & 7)) << 4;   // pre-swizzled chunk
    const char* gA1 = (const char*)A +
        ((size_t)(tile_m + wm * 128 + wn * 16 + (lane >> 3)) << ROWB) + scb;
    const char* gA2 = gA1 + ((size_t)64 << ROWB);
    const char* gBs = (const char*)B +
        ((size_t)(tile_n + wn * 64 + wm * 32 + (lane >> 3)) << ROWB) + scb;
    // LDS staging dests (wave-uniform bases), within a 64KB buffer
    const int dA1 = (wm * 128 + wn * 16) * 128;          // A at [0,32K)
    const int dA2 = dA1 + 8192;                          // +64 rows
    const int dB  = 32768 + (wn * 64 + wm * 32) * 128;   // B at [32K,64K)

    // fragment read bases (within buffer): +mh*8192 +mb*2048 +xk
    const int aB = (wm * 128 + l15) * 128;
    const int bB = 32768 + (wn * 64 + l15) * 128;        // +nh*4096 +nb*2048

    f32x4 acc[8][4];
#pragma unroll
    for (int mb = 0; mb < 8; ++mb)
#pragma unroll
        for (int nb = 0; nb < 4; ++nb) acc[mb][nb] = (f32x4){0.f, 0.f, 0.f, 0.f};

    // prologue: stage tile 0 into buffer 0 (own slices, read order), drain
    gload16(gA1, lds + dA1);
    gload16(gA1 + ((size_t)8 << ROWB), lds + dA1 + 1024);
    gload16(gBs, lds + dB);
    gload16(gBs + ((size_t)8 << ROWB), lds + dB + 1024);
    gload16(gBs + ((size_t)16 << ROWB), lds + dB + 2048);
    gload16(gBs + ((size_t)24 << ROWB), lds + dB + 3072);
    gload16(gA2, lds + dA2);
    gload16(gA2 + ((size_t)8 << ROWB), lds + dA2 + 1024);
    asm volatile("s_waitcnt vmcnt(0)" ::: "memory");
    __builtin_amdgcn_s_barrier();

#define TILE_BODY(T, CB, SB) do {                                            \
    const int ts_ = ((T) + 1 < NT) ? (T) + 1 : NT - 1;                       \
    const size_t tso = (size_t)ts_ * 128;                                    \
    bf16x8 af[8], af2[8], bf[4], bf2[4];                                     \
    /* ---- ph1: read A-low(8) + B-low(4) || stage A-low(next) ---- */       \
    _Pragma("unroll")                                                        \
    for (int mb = 0; mb < 4; ++mb) {                                         \
        af[mb * 2 + 0] = *(const bf16x8*)(lds + (CB) + aB + mb * 2048 + xk0);\
        af[mb * 2 + 1] = *(const bf16x8*)(lds + (CB) + aB + mb * 2048 + xk1);\
    }                                                                        \
    _Pragma("unroll")                                                        \
    for (int nb = 0; nb < 2; ++nb) {                                         \
        bf[nb * 2 + 0] = *(const bf16x8*)(lds + (CB) + bB + nb * 2048 + xk0);\
        bf[nb * 2 + 1] = *(const bf16x8*)(lds + (CB) + bB + nb * 2048 + xk1);\
    }                                                                        \
    gload16(gA1 + tso, lds + (SB) + dA1);                                    \
    gload16(gA1 + tso + ((size_t)8 << ROWB), lds + (SB) + dA1 + 1024);       \
    asm volatile("s_waitcnt lgkmcnt(8)" ::: "memory");                       \
    __builtin_amdgcn_s_barrier();                                            \
    asm volatile("s_waitcnt lgkmcnt(0)" ::: "memory");                       \
    __builtin_amdgcn_s_setprio(1);                                           \
    _Pragma("unroll")                                                        \
    for (int mb = 0; mb < 4; ++mb)                                           \
        _Pragma("unroll")                                                    \
        for (int nb = 0; nb < 2; ++nb)                                       \
            _Pragma("unroll")                                                \
            for (int ks = 0; ks < 2; ++ks)                                   \
                acc[mb][nb] = __builtin_amdgcn_mfma_f32_16x16x32_bf16(       \
                    af[mb * 2 + ks], bf[nb * 2 + ks], acc[mb][nb], 0, 0, 0); \
    __builtin_amdgcn_s_setprio(0);                                           \
    __builtin_amdgcn_s_barrier();                                            \
    /* ---- ph2: read B-high(4) || stage B-part1(next) ---- */               \
    _Pragma("unroll")                                                        \
    for (int nb = 0; nb < 2; ++nb) {                                         \
        bf2[nb * 2 + 0] =                                                    \
            *(const bf16x8*)(lds + (CB) + bB + 4096 + nb * 2048 + xk0);      \
        bf2[nb * 2 + 1] =                                                    \
            *(const bf16x8*)(lds + (CB) + bB + 4096 + nb * 2048 + xk1);      \
    }                                                                        \
    gload16(gBs + tso, lds + (SB) + dB);                                     \
    gload16(gBs + tso + ((size_t)8 << ROWB), lds + (SB) + dB + 1024);        \
    __builtin_amdgcn_s_barrier();                                            \
    asm volatile("s_waitcnt lgkmcnt(0)" ::: "memory");                       \
    __builtin_amdgcn_s_setprio(1);                                           \
    _Pragma("unroll")                                                        \
    for (int mb = 0; mb < 4; ++mb)                                           \
        _Pragma("unroll")                                                    \
        for (int nb = 0; nb < 2; ++nb)                                       \
            _Pragma("unroll")                                                \
            for (int ks = 0; ks < 2; ++ks)                                   \
                acc[mb][2 + nb] = __builtin_amdgcn_mfma_f32_16x16x32_bf16(   \
                    af[mb * 2 + ks], bf2[nb * 2 + ks], acc[mb][2 + nb],      \
                    0, 0, 0);                                                \
    __builtin_amdgcn_s_setprio(0);                                           \
    asm volatile("s_waitcnt vmcnt(4)" ::: "memory");                         \
    __builtin_amdgcn_s_barrier();                                            \
    /* ---- ph3: read A-high(8) || stage B-part2(next) ---- */               \
    _Pragma("unroll")                                                        \
    for (int mb = 0; mb < 4; ++mb) {                                         \
        af2[mb * 2 + 0] =                                                    \
            *(const bf16x8*)(lds + (CB) + aB + 8192 + mb * 2048 + xk0);      \
        af2[mb * 2 + 1] =                                                    \
            *(const bf16x8*)(lds + (CB) + aB + 8192 + mb * 2048 + xk1);      \
    }                                                                        \
    gload16(gBs + tso + ((size_t)16 << ROWB), lds + (SB) + dB + 2048);       \
    gload16(gBs + tso + ((size_t)24 << ROWB), lds + (SB) + dB + 3072);       \
    __builtin_amdgcn_s_barrier();                                            \
    asm volatile("s_waitcnt lgkmcnt(0)" ::: "memory");                       \
    __builtin_amdgcn_s_setprio(1);                                           \
    _Pragma("unroll")                                                        \
    for (int mb = 0; mb < 4; ++mb)                                           \
        _Pragma("unroll")                                                    \
        for (int nb = 0; nb < 2; ++nb)                                       \
            _Pragma("unroll")                                                \
            for (int ks = 0; ks < 2; ++ks)                                   \
                acc[4 + mb][2 + nb] = __builtin_amdgcn_mfma_f32_16x16x32_bf16(\
                    af2[mb * 2 + ks], bf2[nb * 2 + ks], acc[4 + mb][2 + nb], \
                    0, 0, 0);                                                \
    __builtin_amdgcn_s_setprio(0);                                           \
    __builtin_amdgcn_s_barrier();                                            \
    /* ---- ph4: re-read B-low(4) || stage A-high(next) ---- */              \
    _Pragma("unroll")                                                        \
    for (int nb = 0; nb < 2; ++nb) {                                         \
        bf[nb * 2 + 0] = *(const bf16x8*)(lds + (CB) + bB + nb * 2048 + xk0);\
        bf[nb * 2 + 1] = *(const bf16x8*)(lds + (CB) + bB + nb * 2048 + xk1);\
    }                                                                        \
    gload16(gA2 + tso, lds + (SB) + dA2);                                    \
    gload16(gA2 + tso + ((size_t)8 << ROWB), lds + (SB) + dA2 + 1024);       \
    __builtin_amdgcn_s_barrier();                                            \
    asm volatile("s_waitcnt lgkmcnt(0)" ::: "memory");                       \
    __builtin_amdgcn_s_setprio(1);                                           \
    _Pragma("unroll")                                                        \
    for (int mb = 0; mb < 4; ++mb)                                           \
        _Pragma("unroll")                                                    \
        for (int nb = 0; nb < 2; ++nb)                                       \
            _Pragma("unroll")                                                \
            for (int ks = 0; ks < 2; ++ks)                                   \
                acc[4 + mb][nb] = __builtin_amdgcn_mfma_f32_16x16x32_bf16(   \
                    af2[mb * 2 + ks], bf[nb * 2 + ks], acc[4 + mb][nb],      \
                    0, 0, 0);                                                \
    __builtin_amdgcn_s_setprio(0);                                           \
    asm volatile("s_waitcnt vmcnt(2)" ::: "memory");                         \
    __builtin_amdgcn_s_barrier();                                            \
} while (0)

    for (int t = 0; t < NT; t += 2) {
        TILE_BODY(t,     0,     65536);
        TILE_BODY(t + 1, 65536, 0);
    }
#undef TILE_BODY

    // epilogue: C/D layout col=lane&15, row=(lane>>4)*4+j
    const float gs = sg1[0] * sg2[0];
    const int row0 = tile_m + wm * 128 + (cb4 << 2);
    const int col0 = tile_n + wn * 64 + l15;
    float bv[4];
#pragma unroll
    for (int nb = 0; nb < 4; ++nb) bv[nb] = bias[col0 + nb * 16];
#pragma unroll
    for (int mb = 0; mb < 8; ++mb)
#pragma unroll
        for (int nb = 0; nb < 4; ++nb) {
            const int col = col0 + nb * 16;
#pragma unroll
            for (int j = 0; j < 4; ++j)
                out[(size_t)(row0 + mb * 16 + j) * N + col] =
                    acc[mb][nb][j] * gs + bv[nb];
        }
}

// ---------------- fallback: fused-dequant 128^2 GEMM (ws too small) ----------------
__global__ __launch_bounds__(256) void gemm_fused_kernel(
        const float* __restrict__ qx, const float* __restrict__ sx,
        const float* __restrict__ qw, const float* __restrict__ sw,
        const float* __restrict__ sg1, const float* __restrict__ sg2,
        const float* __restrict__ bias,
        float* __restrict__ out, int M, int N) {
    __shared__ __align__(16) unsigned short As[128 * 32];
    __shared__ __align__(16) unsigned short Bs[128 * 32];
    const int tid  = threadIdx.x;
    const int lane = tid & 63;
    const int wid  = tid >> 6;
    const int tile_n = blockIdx.x * 128;
    const int tile_m = blockIdx.y * 128;
    const int wm = wid >> 1, wn = wid & 1;
    f32x4 acc[16];
#pragma unroll
    for (int i = 0; i < 16; ++i) acc[i] = (f32x4){0.f, 0.f, 0.f, 0.f};
    const int l15 = lane & 15;
    const int lk  = (lane >> 4) * 8;
    for (int kt = 0; kt < K_DIM / 32; ++kt) {
#pragma unroll
        for (int cc = 0; cc < 2; ++cc) {
            const int c   = tid + cc * 256;
            const int row = c >> 2;
            const int col = (c & 3) * 8;
            const int gk  = kt * 32 + col;
            {
                const float* qp = qx + (long)(tile_m + row) * K_DIM + gk;
                float s = sx[(long)(tile_m + row) * (K_DIM / 16) + (gk >> 4)];
                float4 a0 = *(const float4*)qp;
                float4 a1 = *(const float4*)(qp + 4);
                union { unsigned short h[8]; uint4 u; } o;
                o.h[0] = f2bf(a0.x * s); o.h[1] = f2bf(a0.y * s);
                o.h[2] = f2bf(a0.z * s); o.h[3] = f2bf(a0.w * s);
                o.h[4] = f2bf(a1.x * s); o.h[5] = f2bf(a1.y * s);
                o.h[6] = f2bf(a1.z * s); o.h[7] = f2bf(a1.w * s);
                *(uint4*)&As[row * 32 + col] = o.u;
            }
            {
                const float* qp = qw + (long)(tile_n + row) * K_DIM + gk;
                float s = sw[(long)(tile_n + row) * (K_DIM / 16) + (gk >> 4)];
                float4 a0 = *(const float4*)qp;
                float4 a1 = *(const float4*)(qp + 4);
                union { unsigned short h[8]; uint4 u; } o;
                o.h[0] = f2bf(a0.x * s); o.h[1] = f2bf(a0.y * s);
                o.h[2] = f2bf(a0.z * s); o.h[3] = f2bf(a0.w * s);
                o.h[4] = f2bf(a1.x * s); o.h[5] = f2bf(a1.y * s);
                o.h[6] = f2bf(a1.z * s); o.h[7] = f2bf(a1.w * s);
                *(uint4*)&Bs[row * 32 + col] = o.u;
            }
        }
        __syncthreads();
        const unsigned short* pa = As + (wm * 64 + l15) * 32 + lk;
        const unsigned short* pb = Bs + (wn * 64 + l15) * 32 + lk;
        bf16x8 a[4], b[4];
#pragma unroll
        for (int i = 0; i < 4; ++i) {
            a[i] = *(const bf16x8*)(pa + i * 16 * 32);
            b[i] = *(const bf16x8*)(pb + i * 16 * 32);
        }
#pragma unroll
        for (int mi = 0; mi < 4; ++mi)
#pragma unroll
            for (int ni = 0; ni < 4; ++ni)
                acc[mi * 4 + ni] = __builtin_amdgcn_mfma_f32_16x16x32_bf16(
                    a[mi], b[ni], acc[mi * 4 + ni], 0, 0, 0);
        __syncthreads();
    }
    const float gs = sg1[0] * sg2[0];
    const int row0 = tile_m + wm * 64 + (lane >> 4) * 4;
    const int col0 = tile_n + wn * 64 + l15;
#pragma unroll
    for (int mi = 0; mi < 4; ++mi)
#pragma unroll
        for (int ni = 0; ni < 4; ++ni) {
            const int col = col0 + ni * 16;
            const float bv = bias[col];
#pragma unroll
            for (int j = 0; j < 4; ++j)
                out[(long)(row0 + mi * 16 + j) * N + col] =
                    acc[mi * 4 + ni][j] * gs + bv;
        }
}

extern "C" void kernel_launch(void* const* d_in, const int* in_sizes, int n_in,
                              void* d_out, int out_size, void* d_ws, size_t ws_size,
                              hipStream_t stream) {
    const float* qx   = (const float*)d_in[0];
    const float* sx   = (const float*)d_in[1];
    const float* sc   = (const float*)d_in[2];
    const float* qw   = (const float*)d_in[3];
    const float* sw   = (const float*)d_in[4];
    const float* swg  = (const float*)d_in[5];
    const float* bias = (const float*)d_in[6];
    float* out = (float*)d_out;

    const int M = in_sizes[0] / K_DIM;   // 8192
    const int N = in_sizes[3] / K_DIM;   // 4096

    const size_t needA = (size_t)M * K_DIM * sizeof(unsigned short);
    const size_t needB = (size_t)N * K_DIM * sizeof(unsigned short);

    if (ws_size >= needA + needB) {
        unsigned short* xd = (unsigned short*)d_ws;
        unsigned short* wd = (unsigned short*)((char*)d_ws + needA);
        long t8x = (long)M * K_DIM / 8;
        long t8w = (long)N * K_DIM / 8;
        long tot = t8x + t8w;
        dequant2_kernel<<<(int)((tot + 255) / 256), 256, 0, stream>>>(
            qx, sx, xd, t8x, qw, sw, wd, t8w);
        const int nwg = (M / 256) * (N / 256);
        gemm256_kernel<<<nwg, 512, 0, stream>>>(xd, wd, sc, swg, bias, out, M, N);
    } else {
        dim3 grid(N / 128, M / 128);
        gemm_fused_kernel<<<grid, 256, 0, stream>>>(
            qx, sx, qw, sw, sc, swg, bias, out, M, N);
    }
}